// Round 6
// baseline (232.821 us; speedup 1.0000x reference)
//
#include <hip/hip_runtime.h>

#define Bn 2
#define Nn 384
#define Dn 256
#define Rn 128
#define Sn 64
#define BNn (Bn*Nn)
#define NEG_LOG2E -1.44269504088896f

typedef short short8 __attribute__((ext_vector_type(8)));
typedef float f32x4 __attribute__((ext_vector_type(4)));
typedef unsigned int uint;
typedef unsigned short ushort;

static __device__ __forceinline__ float fast_sigmoid(float x) {
    return __builtin_amdgcn_rcpf(1.0f + __expf(-x));
}
static __device__ __forceinline__ ushort f2bf(float f) {
    uint u = __float_as_uint(f);
    uint r = (u + 0x7fffu + ((u >> 16) & 1u)) >> 16;   // RNE
    return (ushort)r;
}
static __device__ __forceinline__ float bf2f(ushort u) {
    return __uint_as_float(((uint)u) << 16);
}

// ================= K1: prep = zero-stats + projections + VdT transpose =================
// grid 896 x 256. Blocks 0..767: proj of 1 t-row each. Blocks 768..895: VdT prep.
__global__ __launch_bounds__(256)
void prep_kernel(const float* __restrict__ t,
                 const float* __restrict__ Qd, const float* __restrict__ Kd,
                 const float* __restrict__ Vd,
                 const float* __restrict__ Qs, const float* __restrict__ Ks,
                 float* __restrict__ q, float* __restrict__ k,
                 ushort* __restrict__ qdb, ushort* __restrict__ kdb,
                 ushort* __restrict__ VdT, float* __restrict__ stats) {
    const int bi = blockIdx.x;
    const int tid = threadIdx.x;
    if (bi >= BNn) {
        // VdT[d][r] = bf16(-log2(e) * Vd[r][d])  (pre-scaled for exp2-based gate)
        const int idx = (bi - BNn) * 256 + tid;       // 0..32767
        const int d = idx >> 7, r = idx & 127;
        VdT[idx] = f2bf(NEG_LOG2E * Vd[(size_t)r * Dn + d]);
        if (bi == BNn && tid < 4) stats[tid] = 0.0f;
        return;
    }
    __shared__ float trow[Dn];
    trow[tid] = t[(size_t)bi * Dn + tid];
    __syncthreads();
    // qd / kd (bf16): all 256 threads, one output col each
    {
        const float* W = (tid < 128) ? Qd : Kd;
        ushort* ob = (tid < 128) ? qdb : kdb;
        const int col = tid & 127;
        float a0 = 0.f;
        for (int kk = 0; kk < Dn; kk += 4) {
            float4 tv = *(const float4*)&trow[kk];
            a0 += tv.x * W[(size_t)(kk + 0) * 128 + col]
                + tv.y * W[(size_t)(kk + 1) * 128 + col]
                + tv.z * W[(size_t)(kk + 2) * 128 + col]
                + tv.w * W[(size_t)(kk + 3) * 128 + col];
        }
        ob[(size_t)bi * 128 + col] = f2bf(a0);
    }
    // q / k (fp32): threads < 128, one output col each
    if (tid < 128) {
        const float* W = (tid < 64) ? Qs : Ks;
        float* of = (tid < 64) ? q : k;
        const int col = tid & 63;
        float a0 = 0.f;
        for (int kk = 0; kk < Dn; kk += 4) {
            float4 tv = *(const float4*)&trow[kk];
            a0 += tv.x * W[(size_t)(kk + 0) * 64 + col]
                + tv.y * W[(size_t)(kk + 1) * 64 + col]
                + tv.z * W[(size_t)(kk + 2) * 64 + col]
                + tv.w * W[(size_t)(kk + 3) * 64 + col];
        }
        of[(size_t)bi * 64 + col] = a0;
    }
}

// ================= K2: s_sym + off-diag stats (shfl-based reduction) =================
__global__ __launch_bounds__(256)
void ssym_kernel(const float* __restrict__ q, const float* __restrict__ k,
                 float* __restrict__ ssym, float* __restrict__ stats) {
    __shared__ float qi[16][68], ki[16][68], qj[16][68], kj[16][68];
    __shared__ float part[8];
    const int b = blockIdx.z, it = blockIdx.x, jt = blockIdx.y;
    const int tid = threadIdx.x;
    const int r0 = tid >> 6, c = tid & 63;
#pragma unroll
    for (int p = 0; p < 4; ++p) {
        int row = r0 + 4 * p;
        qi[row][c] = q[((size_t)(b * Nn + it * 16 + row)) * Sn + c];
        ki[row][c] = k[((size_t)(b * Nn + it * 16 + row)) * Sn + c];
        qj[row][c] = q[((size_t)(b * Nn + jt * 16 + row)) * Sn + c];
        kj[row][c] = k[((size_t)(b * Nn + jt * 16 + row)) * Sn + c];
    }
    __syncthreads();
    const int ti = tid >> 4, tj = tid & 15;
    float acc = 0.0f;
#pragma unroll
    for (int dd = 0; dd < Sn; dd += 4) {
        float4 a  = *(const float4*)&qi[ti][dd];
        float4 bb = *(const float4*)&kj[tj][dd];
        float4 cc = *(const float4*)&qj[tj][dd];
        float4 d  = *(const float4*)&ki[ti][dd];
        acc += a.x * bb.x + a.y * bb.y + a.z * bb.z + a.w * bb.w
             + cc.x * d.x + cc.y * d.y + cc.z * d.z + cc.w * d.w;
    }
    const float sval = acc * 0.0625f;
    const int gi = it * 16 + ti, gj = jt * 16 + tj;
    ssym[((size_t)(b * Nn + gi)) * Nn + gj] = sval;
    const float v = (gi == gj) ? 0.0f : sval;

    float vs = v, v2 = v * v;
#pragma unroll
    for (int mask = 32; mask > 0; mask >>= 1) {
        vs += __shfl_xor(vs, mask);
        v2 += __shfl_xor(v2, mask);
    }
    const int lane = tid & 63, wave = tid >> 6;
    if (lane == 0) { part[wave] = vs; part[4 + wave] = v2; }
    __syncthreads();
    if (tid == 0) {
        atomicAdd(&stats[b * 2 + 0], part[0] + part[1] + part[2] + part[3]);
        atomicAdd(&stats[b * 2 + 1], part[4] + part[5] + part[6] + part[7]);
    }
}

// ================= K3: m[row] (stats finalized inline) =================
__global__ __launch_bounds__(256)
void m_kernel(const float* __restrict__ ssym, const float* __restrict__ stats,
              const float* __restrict__ a_l, const float* __restrict__ b_l,
              float* __restrict__ m) {
    __shared__ float part[4];
    const int row = blockIdx.x;
    const int b = row / Nn;
    const float cnt_inv = 1.0f / (float)(Nn * (Nn - 1));
    const float mu = stats[b * 2 + 0] * cnt_inv;
    const float var = stats[b * 2 + 1] * cnt_inv - mu * mu;
    const float isg = rsqrtf(var + 1e-6f);
    const float a = a_l[0], bbias = b_l[0];
    const int tid = threadIdx.x;
    float sum = __expf(a * (ssym[(size_t)row * Nn + tid] - mu) * isg + bbias);
    if (tid < 128)
        sum += __expf(a * (ssym[(size_t)row * Nn + 256 + tid] - mu) * isg + bbias);
#pragma unroll
    for (int mask = 32; mask > 0; mask >>= 1) sum += __shfl_xor(sum, mask);
    if ((tid & 63) == 0) part[tid >> 6] = sum;
    __syncthreads();
    if (tid == 0) m[row] = 1.0f / (part[0] + part[1] + part[2] + part[3] + 1e-6f);
}

// ================= K4: pair kernel v6 — u/w factorization, FRAG-ORDERED LDS ============
// kappa_diff (scaled by -log2e) = U - W:
//   U = MFMA(A = u[d,r], B = kd_j[r]),  u = VdT_scaled[d,r] * qd_i[r]
//   W = MFMA(A = w[d,r], B = qd_j[r]),  w = VdT_scaled[d,r] * kd_i[r]
// grid 4*BNn: blk>>2 = (b,i), blk&3 = d-quarter (64 d per block, 16 d per wave).
// HISTORY (do not regress):
//   r1: (256,6) -> 40-VGPR cap -> spill (640 MB HBM). Never min-waves > 4.
//   r3: d-half keeps 64 persistent A-frag VGPRs -> peak ~140 > 128 -> spill (108 MB W).
//   r4: global-direct B gathers -> latency-bound (4.6% MFMA, 48 VGPR no concurrency).
//   r5: row-major LDS + (row&7)<<4 XOR -> slot (ks*4+quad)^(ln&7) aliases 8 lanes/slot
//       -> 9.4M bank conflicts (19% of cycles). Swizzled row-major is WRONG here.
// v6: FRAG-ORDERED LDS. Tile stored as frag[jsub][ks][quad][ln][8 bf16]:
//   read  addr(lane; s,ks) = lane*16 + s*4096 + ks*1024   (wave reads contiguous 1 KB)
//   write addr(tid; item)  = tid*16 (+4096)               (wave writes contiguous 1 KB)
// Both sides lane-linear => conflict-free by construction. tj prefetched 1 subtile ahead.
__global__ __launch_bounds__(256, 4)
void pair_kernel(const float* __restrict__ t, const float* __restrict__ ssym,
                 const float* __restrict__ mptr, const float* __restrict__ stats,
                 const float* __restrict__ a_l, const float* __restrict__ b_l,
                 const ushort* __restrict__ qdb, const ushort* __restrict__ kdb,
                 const ushort* __restrict__ VdT, float* __restrict__ out) {
    __shared__ ushort qs_lds[2][4096];   // 2 x 8 KB, frag-ordered
    __shared__ ushort ks_lds[2][4096];   // 2 x 8 KB
    __shared__ float alpha_s[Nn];
    __shared__ float part[4];

    const int blk = blockIdx.x;
    const int bi = blk >> 2;
    const int dq = blk & 3;
    const int b = bi / Nn;
    const int i = bi - b * Nn;
    const int tid = threadIdx.x;
    const int wave = tid >> 6, lane = tid & 63;
    const int ln = lane & 15, quad = lane >> 4;
    const int wd0 = dq * 64 + wave * 16;     // this wave's 16-d row tile

    // ---- inline alpha row (shfl reduce) ----
    {
        const float cnt_inv = 1.0f / (float)(Nn * (Nn - 1));
        const float mu = stats[b * 2 + 0] * cnt_inv;
        const float var = stats[b * 2 + 1] * cnt_inv - mu * mu;
        const float isg = rsqrtf(var + 1e-6f);
        const float a = a_l[0], bbias = b_l[0];
        float A0, am0, A1 = 0.f, am1 = 0.f;
        {
            float s0 = ssym[(size_t)bi * Nn + tid];
            A0 = fast_sigmoid(a * (s0 - mu) * isg + bbias);
            am0 = A0 * mptr[b * Nn + tid];
        }
        if (tid < 128) {
            float s1 = ssym[(size_t)bi * Nn + 256 + tid];
            A1 = fast_sigmoid(a * (s1 - mu) * isg + bbias);
            am1 = A1 * mptr[b * Nn + 256 + tid];
        }
        float sum = am0 + am1;
#pragma unroll
        for (int mask = 32; mask > 0; mask >>= 1) sum += __shfl_xor(sum, mask);
        if (lane == 0) part[wave] = sum;
        __syncthreads();
        const float inv = 1.0f / (part[0] + part[1] + part[2] + part[3] + 1e-6f);
        alpha_s[tid] = (tid == i) ? 0.f : A0 * am0 * inv;
        if (tid < 128)
            alpha_s[256 + tid] = ((256 + tid) == i) ? 0.f : A1 * am1 * inv;
        // covered by the prologue barrier below
    }

    // ---- one-time: A-fragments u = VdTs*qd_i, w = VdTs*kd_i (bf16), 8 short8 = 32 VGPR ----
    // A layout (16x16x32): m = ln (d within 16), k = quad*8+e, r = ks*32 + k.
    short8 uf[4], wf[4];
    {
        const size_t qrow = (size_t)bi * Rn;
#pragma unroll
        for (int ks = 0; ks < 4; ++ks) {
            short8 qv = *(const short8*)&qdb[qrow + ks * 32 + quad * 8];
            short8 kv = *(const short8*)&kdb[qrow + ks * 32 + quad * 8];
            short8 vv = *(const short8*)&VdT[(size_t)(wd0 + ln) * Rn + ks * 32 + quad * 8];
            short8 uu, ww;
#pragma unroll
            for (int e = 0; e < 8; ++e) {
                float vf_ = bf2f((ushort)vv[e]);
                uu[e] = (short)f2bf(vf_ * bf2f((ushort)qv[e]));
                ww[e] = (short)f2bf(vf_ * bf2f((ushort)kv[e]));
            }
            uf[ks] = uu;
            wf[ks] = ww;
        }
    }

    float4 tiv = *(const float4*)&t[(size_t)bi * Dn + wd0 + quad * 4];
    float4 outac = make_float4(0.f, 0.f, 0.f, 0.f);

    const ushort* qsrc = qdb + (size_t)b * Nn * Rn;
    const ushort* ksrc = kdb + (size_t)b * Nn * Rn;
    const float* tbase_ = t + (size_t)b * Nn * Dn + wd0 + quad * 4;

    // staging: thread tid covers frag items tid (jsub 0) and tid+256 (jsub 1):
    //   global row = tile + (tid&15) (+16), chunk cch (16B) within the 256B row.
    const int jloc = tid & 15;
    const int cch  = ((tid >> 6) & 3) * 4 + ((tid >> 4) & 3);   // 0..15
    const int wb0  = tid * 16;                                   // LDS byte (jsub 0)

    uint4 sq0, sq1, sk0, sk1;

    // ---- prologue: stage tile 0 into buf 0 ----
    {
        const ushort* q0 = qsrc + (size_t)jloc * Rn + cch * 8;
        const ushort* k0 = ksrc + (size_t)jloc * Rn + cch * 8;
        sq0 = *(const uint4*)q0;  sq1 = *(const uint4*)(q0 + 16 * Rn);
        sk0 = *(const uint4*)k0;  sk1 = *(const uint4*)(k0 + 16 * Rn);
        *(uint4*)((char*)&qs_lds[0][0] + wb0)        = sq0;
        *(uint4*)((char*)&qs_lds[0][0] + wb0 + 4096) = sq1;
        *(uint4*)((char*)&ks_lds[0][0] + wb0)        = sk0;
        *(uint4*)((char*)&ks_lds[0][0] + wb0 + 4096) = sk1;
    }
    __syncthreads();

    // tj prefetch for first subtile
    float4 tj_cur = *(const float4*)&tbase_[(size_t)ln * Dn];

    int cur = 0;
#pragma unroll 1
    for (int tt = 0; tt < Nn / 32; ++tt) {
        // issue next-tile stage loads early (latency hides under this tile's compute)
        const int tn = (tt + 1 < Nn / 32) ? tt + 1 : 0;   // wrapped: last prefetch unused
        {
            const ushort* q0 = qsrc + (size_t)(tn * 32 + jloc) * Rn + cch * 8;
            const ushort* k0 = ksrc + (size_t)(tn * 32 + jloc) * Rn + cch * 8;
            sq0 = *(const uint4*)q0;  sq1 = *(const uint4*)(q0 + 16 * Rn);
            sk0 = *(const uint4*)k0;  sk1 = *(const uint4*)(k0 + 16 * Rn);
        }

        const char* qbuf = (const char*)&qs_lds[cur][0];
        const char* kbuf = (const char*)&ks_lds[cur][0];
        const int lbase = lane * 16;

        // ---- 2 j-subtiles of 16 from LDS ----
#pragma unroll
        for (int s = 0; s < 2; ++s) {
            const int jj = tt * 2 + s;
            const int jn = (jj + 1 < Nn / 16) ? jj + 1 : 0;
            // prefetch tj for the NEXT subtile; current one already in tj_cur
            float4 tj_nxt = *(const float4*)&tbase_[(size_t)(jn * 16 + ln) * Dn];

            f32x4 accU = {0.f, 0.f, 0.f, 0.f}, accW = {0.f, 0.f, 0.f, 0.f};
#pragma unroll
            for (int ks = 0; ks < 4; ++ks) {
                const int off = lbase + s * 4096 + ks * 1024;
                short8 bk = *(const short8*)(kbuf + off);
                short8 bq = *(const short8*)(qbuf + off);
                accU = __builtin_amdgcn_mfma_f32_16x16x32_bf16(uf[ks], bk, accU, 0, 0, 0);
                accW = __builtin_amdgcn_mfma_f32_16x16x32_bf16(wf[ks], bq, accW, 0, 0, 0);
            }
            const float al = alpha_s[jj * 16 + ln];
            float e0 = accU[0] - accW[0];
            float e1 = accU[1] - accW[1];
            float e2 = accU[2] - accW[2];
            float e3 = accU[3] - accW[3];
            float g0 = __builtin_amdgcn_rcpf(1.0f + __builtin_amdgcn_exp2f(e0));
            float g1 = __builtin_amdgcn_rcpf(1.0f + __builtin_amdgcn_exp2f(e1));
            float g2 = __builtin_amdgcn_rcpf(1.0f + __builtin_amdgcn_exp2f(e2));
            float g3 = __builtin_amdgcn_rcpf(1.0f + __builtin_amdgcn_exp2f(e3));
            outac.x += al * g0 * (tiv.x - tj_cur.x);
            outac.y += al * g1 * (tiv.y - tj_cur.y);
            outac.z += al * g2 * (tiv.z - tj_cur.z);
            outac.w += al * g3 * (tiv.w - tj_cur.w);
            tj_cur = tj_nxt;
        }

        // ---- write next tile into the other buffer, then the tile barrier ----
        {
            char* qd_ = (char*)&qs_lds[cur ^ 1][0];
            char* kd_ = (char*)&ks_lds[cur ^ 1][0];
            *(uint4*)(qd_ + wb0)        = sq0;
            *(uint4*)(qd_ + wb0 + 4096) = sq1;
            *(uint4*)(kd_ + wb0)        = sk0;
            *(uint4*)(kd_ + wb0 + 4096) = sk1;
        }
        __syncthreads();
        cur ^= 1;
    }

    // ---- reduce over the 16 j-lanes, write 16 d per wave ----
    {
        float4 v = outac;
#pragma unroll
        for (int mask = 1; mask < 16; mask <<= 1) {
            v.x += __shfl_xor(v.x, mask);
            v.y += __shfl_xor(v.y, mask);
            v.z += __shfl_xor(v.z, mask);
            v.w += __shfl_xor(v.w, mask);
        }
        if (ln == 0) {
            float4 o;
            o.x = tiv.x - v.x;
            o.y = tiv.y - v.y;
            o.z = tiv.z - v.z;
            o.w = tiv.w - v.w;
            *(float4*)&out[(size_t)bi * Dn + wd0 + quad * 4] = o;
        }
    }
}

extern "C" void kernel_launch(void* const* d_in, const int* in_sizes, int n_in,
                              void* d_out, int out_size, void* d_ws, size_t ws_size,
                              hipStream_t stream) {
    const float* t   = (const float*)d_in[0];
    const float* Qd  = (const float*)d_in[1];
    const float* Kd  = (const float*)d_in[2];
    const float* Vd  = (const float*)d_in[3];
    const float* Qs  = (const float*)d_in[4];
    const float* Ks  = (const float*)d_in[5];
    const float* a_l = (const float*)d_in[6];
    const float* b_l = (const float*)d_in[7];
    float* out = (float*)d_out;
    float* ws  = (float*)d_ws;

    float* q     = ws;                          // 768*64
    float* k     = q + BNn * Sn;                // 768*64
    float* ssym  = k + BNn * Sn;                // 768*384
    float* m     = ssym + (size_t)BNn * Nn;     // 768
    float* stats = m + BNn;                     // 8
    ushort* qdb  = (ushort*)(stats + 8);        // 768*128 bf16
    ushort* kdb  = qdb + (size_t)BNn * Rn;      // 768*128 bf16
    ushort* VdT  = kdb + (size_t)BNn * Rn;      // 256*128 bf16 (pre-scaled by -log2e)

    hipLaunchKernelGGL(prep_kernel, dim3(BNn + 128), dim3(256), 0, stream,
                       t, Qd, Kd, Vd, Qs, Ks, q, k, qdb, kdb, VdT, stats);
    hipLaunchKernelGGL(ssym_kernel, dim3(Nn / 16, Nn / 16, Bn), dim3(256), 0, stream,
                       q, k, ssym, stats);
    hipLaunchKernelGGL(m_kernel, dim3(BNn), dim3(256), 0, stream, ssym, stats, a_l, b_l, m);
    hipLaunchKernelGGL(pair_kernel, dim3(BNn * 4), dim3(256), 0, stream,
                       t, ssym, m, stats, a_l, b_l, qdb, kdb, VdT, out);
}

// Round 7
// 186.292 us; speedup vs baseline: 1.2498x; 1.2498x over previous
//
#include <hip/hip_runtime.h>

#define Bn 2
#define Nn 384
#define Dn 256
#define Rn 128
#define Sn 64
#define BNn (Bn*Nn)
#define NEG_LOG2E -1.44269504088896f

typedef short short8 __attribute__((ext_vector_type(8)));
typedef float f32x4 __attribute__((ext_vector_type(4)));
typedef unsigned int uint;
typedef unsigned short ushort;

static __device__ __forceinline__ float fast_sigmoid(float x) {
    return __builtin_amdgcn_rcpf(1.0f + __expf(-x));
}
static __device__ __forceinline__ ushort f2bf(float f) {
    uint u = __float_as_uint(f);
    uint r = (u + 0x7fffu + ((u >> 16) & 1u)) >> 16;   // RNE
    return (ushort)r;
}
static __device__ __forceinline__ float bf2f(ushort u) {
    return __uint_as_float(((uint)u) << 16);
}

// ================= K1: prep = zero-stats + projections + VdT transpose =================
// grid 896 x 256. Blocks 0..767: proj of 1 t-row each. Blocks 768..895: VdT prep.
__global__ __launch_bounds__(256)
void prep_kernel(const float* __restrict__ t,
                 const float* __restrict__ Qd, const float* __restrict__ Kd,
                 const float* __restrict__ Vd,
                 const float* __restrict__ Qs, const float* __restrict__ Ks,
                 float* __restrict__ q, float* __restrict__ k,
                 ushort* __restrict__ qdb, ushort* __restrict__ kdb,
                 ushort* __restrict__ VdT, float* __restrict__ stats) {
    const int bi = blockIdx.x;
    const int tid = threadIdx.x;
    if (bi >= BNn) {
        // VdT[d][r] = bf16(-log2(e) * Vd[r][d])  (pre-scaled for exp2-based gate)
        const int idx = (bi - BNn) * 256 + tid;       // 0..32767
        const int d = idx >> 7, r = idx & 127;
        VdT[idx] = f2bf(NEG_LOG2E * Vd[(size_t)r * Dn + d]);
        if (bi == BNn && tid < 4) stats[tid] = 0.0f;
        return;
    }
    __shared__ float trow[Dn];
    trow[tid] = t[(size_t)bi * Dn + tid];
    __syncthreads();
    // qd / kd (bf16): all 256 threads, one output col each
    {
        const float* W = (tid < 128) ? Qd : Kd;
        ushort* ob = (tid < 128) ? qdb : kdb;
        const int col = tid & 127;
        float a0 = 0.f;
        for (int kk = 0; kk < Dn; kk += 4) {
            float4 tv = *(const float4*)&trow[kk];
            a0 += tv.x * W[(size_t)(kk + 0) * 128 + col]
                + tv.y * W[(size_t)(kk + 1) * 128 + col]
                + tv.z * W[(size_t)(kk + 2) * 128 + col]
                + tv.w * W[(size_t)(kk + 3) * 128 + col];
        }
        ob[(size_t)bi * 128 + col] = f2bf(a0);
    }
    // q / k (fp32): threads < 128, one output col each
    if (tid < 128) {
        const float* W = (tid < 64) ? Qs : Ks;
        float* of = (tid < 64) ? q : k;
        const int col = tid & 63;
        float a0 = 0.f;
        for (int kk = 0; kk < Dn; kk += 4) {
            float4 tv = *(const float4*)&trow[kk];
            a0 += tv.x * W[(size_t)(kk + 0) * 64 + col]
                + tv.y * W[(size_t)(kk + 1) * 64 + col]
                + tv.z * W[(size_t)(kk + 2) * 64 + col]
                + tv.w * W[(size_t)(kk + 3) * 64 + col];
        }
        of[(size_t)bi * 64 + col] = a0;
    }
}

// ================= K2: s_sym + off-diag stats (shfl-based reduction) =================
__global__ __launch_bounds__(256)
void ssym_kernel(const float* __restrict__ q, const float* __restrict__ k,
                 float* __restrict__ ssym, float* __restrict__ stats) {
    __shared__ float qi[16][68], ki[16][68], qj[16][68], kj[16][68];
    __shared__ float part[8];
    const int b = blockIdx.z, it = blockIdx.x, jt = blockIdx.y;
    const int tid = threadIdx.x;
    const int r0 = tid >> 6, c = tid & 63;
#pragma unroll
    for (int p = 0; p < 4; ++p) {
        int row = r0 + 4 * p;
        qi[row][c] = q[((size_t)(b * Nn + it * 16 + row)) * Sn + c];
        ki[row][c] = k[((size_t)(b * Nn + it * 16 + row)) * Sn + c];
        qj[row][c] = q[((size_t)(b * Nn + jt * 16 + row)) * Sn + c];
        kj[row][c] = k[((size_t)(b * Nn + jt * 16 + row)) * Sn + c];
    }
    __syncthreads();
    const int ti = tid >> 4, tj = tid & 15;
    float acc = 0.0f;
#pragma unroll
    for (int dd = 0; dd < Sn; dd += 4) {
        float4 a  = *(const float4*)&qi[ti][dd];
        float4 bb = *(const float4*)&kj[tj][dd];
        float4 cc = *(const float4*)&qj[tj][dd];
        float4 d  = *(const float4*)&ki[ti][dd];
        acc += a.x * bb.x + a.y * bb.y + a.z * bb.z + a.w * bb.w
             + cc.x * d.x + cc.y * d.y + cc.z * d.z + cc.w * d.w;
    }
    const float sval = acc * 0.0625f;
    const int gi = it * 16 + ti, gj = jt * 16 + tj;
    ssym[((size_t)(b * Nn + gi)) * Nn + gj] = sval;
    const float v = (gi == gj) ? 0.0f : sval;

    float vs = v, v2 = v * v;
#pragma unroll
    for (int mask = 32; mask > 0; mask >>= 1) {
        vs += __shfl_xor(vs, mask);
        v2 += __shfl_xor(v2, mask);
    }
    const int lane = tid & 63, wave = tid >> 6;
    if (lane == 0) { part[wave] = vs; part[4 + wave] = v2; }
    __syncthreads();
    if (tid == 0) {
        atomicAdd(&stats[b * 2 + 0], part[0] + part[1] + part[2] + part[3]);
        atomicAdd(&stats[b * 2 + 1], part[4] + part[5] + part[6] + part[7]);
    }
}

// ================= K3: m[row] (stats finalized inline) =================
__global__ __launch_bounds__(256)
void m_kernel(const float* __restrict__ ssym, const float* __restrict__ stats,
              const float* __restrict__ a_l, const float* __restrict__ b_l,
              float* __restrict__ m) {
    __shared__ float part[4];
    const int row = blockIdx.x;
    const int b = row / Nn;
    const float cnt_inv = 1.0f / (float)(Nn * (Nn - 1));
    const float mu = stats[b * 2 + 0] * cnt_inv;
    const float var = stats[b * 2 + 1] * cnt_inv - mu * mu;
    const float isg = rsqrtf(var + 1e-6f);
    const float a = a_l[0], bbias = b_l[0];
    const int tid = threadIdx.x;
    float sum = __expf(a * (ssym[(size_t)row * Nn + tid] - mu) * isg + bbias);
    if (tid < 128)
        sum += __expf(a * (ssym[(size_t)row * Nn + 256 + tid] - mu) * isg + bbias);
#pragma unroll
    for (int mask = 32; mask > 0; mask >>= 1) sum += __shfl_xor(sum, mask);
    if ((tid & 63) == 0) part[tid >> 6] = sum;
    __syncthreads();
    if (tid == 0) m[row] = 1.0f / (part[0] + part[1] + part[2] + part[3] + 1e-6f);
}

// ================= K4: pair kernel v7 — frag-ordered+XOR LDS, coalesced staging ========
// kappa_diff (scaled by -log2e) = U - W:
//   U = MFMA(A = u[d,r], B = kd_j[r]),  u = VdT_scaled[d,r] * qd_i[r]
//   W = MFMA(A = w[d,r], B = qd_j[r]),  w = VdT_scaled[d,r] * kd_i[r]
// grid 4*BNn: blk>>2 = (b,i), blk&3 = d-quarter (64 d per block, 16 d per wave).
// HISTORY (do not regress):
//   r1: (256,6) -> 40-VGPR cap -> spill (640 MB HBM). Never min-waves > 4.
//   r3: d-half keeps 64 persistent A-frag VGPRs -> peak ~140 > 128 -> spill (108 MB W).
//   r4: global-direct B gathers -> latency-bound (4.6% MFMA). B must be LDS-fed.
//   r5: row-major LDS + (row&7)<<4 XOR -> 8 lanes/slot alias -> 9.4M conflicts (19% cyc).
//   r6: frag-ordered LDS fixed conflicts (9.4M->0) BUT moved the permutation to the
//       GLOBAL side -> 16-segment staging gathers -> 81->129us. Coalescing lost > LDS won.
// v7: permutation lives in the DS_WRITE addresses (reg-staged scatter is free to do so):
//   slot(jr,ch) byte = (ch>>2)*1024 + (ch&3)*256 + (jr^(ch&7))*16   [+4096 per jsub]
//   - global load: thread tid reads row tid>>4, chunk tid&15 -> wave = 1024 B contiguous.
//   - ds_write cols: (jr^(l&7))&7 -> 8 lanes/column, conflict-free.
//   - ds_read (ks,quad,ln): jr=ln, ch=ks*4+quad -> col (ln^((ks&1)*4+quad))&7, uniform.
__global__ __launch_bounds__(256, 4)
void pair_kernel(const float* __restrict__ t, const float* __restrict__ ssym,
                 const float* __restrict__ mptr, const float* __restrict__ stats,
                 const float* __restrict__ a_l, const float* __restrict__ b_l,
                 const ushort* __restrict__ qdb, const ushort* __restrict__ kdb,
                 const ushort* __restrict__ VdT, float* __restrict__ out) {
    __shared__ ushort qs_lds[2][4096];   // 2 x 8 KB, frag-ordered+swizzled
    __shared__ ushort ks_lds[2][4096];   // 2 x 8 KB
    __shared__ float alpha_s[Nn];
    __shared__ float part[4];

    const int blk = blockIdx.x;
    const int bi = blk >> 2;
    const int dq = blk & 3;
    const int b = bi / Nn;
    const int i = bi - b * Nn;
    const int tid = threadIdx.x;
    const int wave = tid >> 6, lane = tid & 63;
    const int ln = lane & 15, quad = lane >> 4;
    const int wd0 = dq * 64 + wave * 16;     // this wave's 16-d row tile

    // ---- inline alpha row (shfl reduce) ----
    {
        const float cnt_inv = 1.0f / (float)(Nn * (Nn - 1));
        const float mu = stats[b * 2 + 0] * cnt_inv;
        const float var = stats[b * 2 + 1] * cnt_inv - mu * mu;
        const float isg = rsqrtf(var + 1e-6f);
        const float a = a_l[0], bbias = b_l[0];
        float A0, am0, A1 = 0.f, am1 = 0.f;
        {
            float s0 = ssym[(size_t)bi * Nn + tid];
            A0 = fast_sigmoid(a * (s0 - mu) * isg + bbias);
            am0 = A0 * mptr[b * Nn + tid];
        }
        if (tid < 128) {
            float s1 = ssym[(size_t)bi * Nn + 256 + tid];
            A1 = fast_sigmoid(a * (s1 - mu) * isg + bbias);
            am1 = A1 * mptr[b * Nn + 256 + tid];
        }
        float sum = am0 + am1;
#pragma unroll
        for (int mask = 32; mask > 0; mask >>= 1) sum += __shfl_xor(sum, mask);
        if (lane == 0) part[wave] = sum;
        __syncthreads();
        const float inv = 1.0f / (part[0] + part[1] + part[2] + part[3] + 1e-6f);
        alpha_s[tid] = (tid == i) ? 0.f : A0 * am0 * inv;
        if (tid < 128)
            alpha_s[256 + tid] = ((256 + tid) == i) ? 0.f : A1 * am1 * inv;
        // covered by the prologue barrier below
    }

    // ---- one-time: A-fragments u = VdTs*qd_i, w = VdTs*kd_i (bf16), 8 short8 = 32 VGPR ----
    // A layout (16x16x32): m = ln (d within 16), k = quad*8+e, r = ks*32 + k.
    short8 uf[4], wf[4];
    {
        const size_t qrow = (size_t)bi * Rn;
#pragma unroll
        for (int ks = 0; ks < 4; ++ks) {
            short8 qv = *(const short8*)&qdb[qrow + ks * 32 + quad * 8];
            short8 kv = *(const short8*)&kdb[qrow + ks * 32 + quad * 8];
            short8 vv = *(const short8*)&VdT[(size_t)(wd0 + ln) * Rn + ks * 32 + quad * 8];
            short8 uu, ww;
#pragma unroll
            for (int e = 0; e < 8; ++e) {
                float vf_ = bf2f((ushort)vv[e]);
                uu[e] = (short)f2bf(vf_ * bf2f((ushort)qv[e]));
                ww[e] = (short)f2bf(vf_ * bf2f((ushort)kv[e]));
            }
            uf[ks] = uu;
            wf[ks] = ww;
        }
    }

    float4 tiv = *(const float4*)&t[(size_t)bi * Dn + wd0 + quad * 4];
    float4 outac = make_float4(0.f, 0.f, 0.f, 0.f);

    const ushort* qsrc = qdb + (size_t)b * Nn * Rn;
    const ushort* ksrc = kdb + (size_t)b * Nn * Rn;
    const float* tbase_ = t + (size_t)b * Nn * Dn + wd0 + quad * 4;

    // staging: thread tid loads global rows (tid>>4) and (tid>>4)+16, chunk tid&15
    //   (wave = 1024 contiguous bytes, coalesced), writes to swizzled frag slot.
    const int jr = tid >> 4;                          // 0..15
    const int ch = tid & 15;                          // 16B chunk
    const int wb = (ch >> 2) * 1024 + (ch & 3) * 256 + ((jr ^ (ch & 7)) * 16);

    uint4 sq0, sq1, sk0, sk1;

    // ---- prologue: stage tile 0 into buf 0 ----
    {
        const ushort* q0 = qsrc + (size_t)jr * Rn + ch * 8;
        const ushort* k0 = ksrc + (size_t)jr * Rn + ch * 8;
        sq0 = *(const uint4*)q0;  sq1 = *(const uint4*)(q0 + 16 * Rn);
        sk0 = *(const uint4*)k0;  sk1 = *(const uint4*)(k0 + 16 * Rn);
        *(uint4*)((char*)&qs_lds[0][0] + wb)        = sq0;
        *(uint4*)((char*)&qs_lds[0][0] + wb + 4096) = sq1;
        *(uint4*)((char*)&ks_lds[0][0] + wb)        = sk0;
        *(uint4*)((char*)&ks_lds[0][0] + wb + 4096) = sk1;
    }
    __syncthreads();

    // read-side swizzled lane term: addr(s,ks) = s*4096 + ks*1024 + (lane_off ^ ((ks&1)<<6))
    const int lane_off = ((ln ^ quad) * 16) + quad * 256;

    // tj prefetch for first subtile
    float4 tj_cur = *(const float4*)&tbase_[(size_t)ln * Dn];

    int cur = 0;
#pragma unroll 1
    for (int tt = 0; tt < Nn / 32; ++tt) {
        // issue next-tile stage loads early (latency hides under this tile's compute)
        const int tn = (tt + 1 < Nn / 32) ? tt + 1 : 0;   // wrapped: last prefetch unused
        {
            const ushort* q0 = qsrc + (size_t)(tn * 32 + jr) * Rn + ch * 8;
            const ushort* k0 = ksrc + (size_t)(tn * 32 + jr) * Rn + ch * 8;
            sq0 = *(const uint4*)q0;  sq1 = *(const uint4*)(q0 + 16 * Rn);
            sk0 = *(const uint4*)k0;  sk1 = *(const uint4*)(k0 + 16 * Rn);
        }

        const char* qbuf = (const char*)&qs_lds[cur][0];
        const char* kbuf = (const char*)&ks_lds[cur][0];

        // ---- 2 j-subtiles of 16 from LDS ----
#pragma unroll
        for (int s = 0; s < 2; ++s) {
            const int jj = tt * 2 + s;
            const int jn = (jj + 1 < Nn / 16) ? jj + 1 : 0;
            // prefetch tj for the NEXT subtile; current one already in tj_cur
            float4 tj_nxt = *(const float4*)&tbase_[(size_t)(jn * 16 + ln) * Dn];

            f32x4 accU = {0.f, 0.f, 0.f, 0.f}, accW = {0.f, 0.f, 0.f, 0.f};
#pragma unroll
            for (int ks = 0; ks < 4; ++ks) {
                const int off = s * 4096 + ks * 1024 + (lane_off ^ ((ks & 1) << 6));
                short8 bk = *(const short8*)(kbuf + off);
                short8 bq = *(const short8*)(qbuf + off);
                accU = __builtin_amdgcn_mfma_f32_16x16x32_bf16(uf[ks], bk, accU, 0, 0, 0);
                accW = __builtin_amdgcn_mfma_f32_16x16x32_bf16(wf[ks], bq, accW, 0, 0, 0);
            }
            const float al = alpha_s[jj * 16 + ln];
            float e0 = accU[0] - accW[0];
            float e1 = accU[1] - accW[1];
            float e2 = accU[2] - accW[2];
            float e3 = accU[3] - accW[3];
            float g0 = __builtin_amdgcn_rcpf(1.0f + __builtin_amdgcn_exp2f(e0));
            float g1 = __builtin_amdgcn_rcpf(1.0f + __builtin_amdgcn_exp2f(e1));
            float g2 = __builtin_amdgcn_rcpf(1.0f + __builtin_amdgcn_exp2f(e2));
            float g3 = __builtin_amdgcn_rcpf(1.0f + __builtin_amdgcn_exp2f(e3));
            outac.x += al * g0 * (tiv.x - tj_cur.x);
            outac.y += al * g1 * (tiv.y - tj_cur.y);
            outac.z += al * g2 * (tiv.z - tj_cur.z);
            outac.w += al * g3 * (tiv.w - tj_cur.w);
            tj_cur = tj_nxt;
        }

        // ---- write next tile into the other buffer, then the tile barrier ----
        {
            char* qd_ = (char*)&qs_lds[cur ^ 1][0];
            char* kd_ = (char*)&ks_lds[cur ^ 1][0];
            *(uint4*)(qd_ + wb)        = sq0;
            *(uint4*)(qd_ + wb + 4096) = sq1;
            *(uint4*)(kd_ + wb)        = sk0;
            *(uint4*)(kd_ + wb + 4096) = sk1;
        }
        __syncthreads();
        cur ^= 1;
    }

    // ---- reduce over the 16 j-lanes, write 16 d per wave ----
    {
        float4 v = outac;
#pragma unroll
        for (int mask = 1; mask < 16; mask <<= 1) {
            v.x += __shfl_xor(v.x, mask);
            v.y += __shfl_xor(v.y, mask);
            v.z += __shfl_xor(v.z, mask);
            v.w += __shfl_xor(v.w, mask);
        }
        if (ln == 0) {
            float4 o;
            o.x = tiv.x - v.x;
            o.y = tiv.y - v.y;
            o.z = tiv.z - v.z;
            o.w = tiv.w - v.w;
            *(float4*)&out[(size_t)bi * Dn + wd0 + quad * 4] = o;
        }
    }
}

extern "C" void kernel_launch(void* const* d_in, const int* in_sizes, int n_in,
                              void* d_out, int out_size, void* d_ws, size_t ws_size,
                              hipStream_t stream) {
    const float* t   = (const float*)d_in[0];
    const float* Qd  = (const float*)d_in[1];
    const float* Kd  = (const float*)d_in[2];
    const float* Vd  = (const float*)d_in[3];
    const float* Qs  = (const float*)d_in[4];
    const float* Ks  = (const float*)d_in[5];
    const float* a_l = (const float*)d_in[6];
    const float* b_l = (const float*)d_in[7];
    float* out = (float*)d_out;
    float* ws  = (float*)d_ws;

    float* q     = ws;                          // 768*64
    float* k     = q + BNn * Sn;                // 768*64
    float* ssym  = k + BNn * Sn;                // 768*384
    float* m     = ssym + (size_t)BNn * Nn;     // 768
    float* stats = m + BNn;                     // 8
    ushort* qdb  = (ushort*)(stats + 8);        // 768*128 bf16
    ushort* kdb  = qdb + (size_t)BNn * Rn;      // 768*128 bf16
    ushort* VdT  = kdb + (size_t)BNn * Rn;      // 256*128 bf16 (pre-scaled by -log2e)

    hipLaunchKernelGGL(prep_kernel, dim3(BNn + 128), dim3(256), 0, stream,
                       t, Qd, Kd, Vd, Qs, Ks, q, k, qdb, kdb, VdT, stats);
    hipLaunchKernelGGL(ssym_kernel, dim3(Nn / 16, Nn / 16, Bn), dim3(256), 0, stream,
                       q, k, ssym, stats);
    hipLaunchKernelGGL(m_kernel, dim3(BNn), dim3(256), 0, stream, ssym, stats, a_l, b_l, m);
    hipLaunchKernelGGL(pair_kernel, dim3(BNn * 4), dim3(256), 0, stream,
                       t, ssym, m, stats, a_l, b_l, qdb, kdb, VdT, out);
}

// Round 8
// 180.585 us; speedup vs baseline: 1.2893x; 1.0316x over previous
//
#include <hip/hip_runtime.h>

#define Bn 2
#define Nn 384
#define Dn 256
#define Rn 128
#define Sn 64
#define BNn (Bn*Nn)
#define NEG_LOG2E -1.44269504088896f

typedef short short8 __attribute__((ext_vector_type(8)));
typedef float f32x4 __attribute__((ext_vector_type(4)));
typedef unsigned int uint;
typedef unsigned short ushort;

static __device__ __forceinline__ float fast_sigmoid(float x) {
    return __builtin_amdgcn_rcpf(1.0f + __expf(-x));
}
static __device__ __forceinline__ ushort f2bf(float f) {
    uint u = __float_as_uint(f);
    uint r = (u + 0x7fffu + ((u >> 16) & 1u)) >> 16;   // RNE
    return (ushort)r;
}
static __device__ __forceinline__ float bf2f(ushort u) {
    return __uint_as_float(((uint)u) << 16);
}

// ================= K1: prep = zero-stats + projections + VdT transpose =================
// grid 896 x 256. Blocks 0..767: proj of 1 t-row each. Blocks 768..895: VdT prep.
__global__ __launch_bounds__(256)
void prep_kernel(const float* __restrict__ t,
                 const float* __restrict__ Qd, const float* __restrict__ Kd,
                 const float* __restrict__ Vd,
                 const float* __restrict__ Qs, const float* __restrict__ Ks,
                 float* __restrict__ q, float* __restrict__ k,
                 ushort* __restrict__ qdb, ushort* __restrict__ kdb,
                 ushort* __restrict__ VdT, float* __restrict__ stats) {
    const int bi = blockIdx.x;
    const int tid = threadIdx.x;
    if (bi >= BNn) {
        // VdT[d][r] = bf16(-log2(e) * Vd[r][d])  (pre-scaled for exp2-based gate)
        const int idx = (bi - BNn) * 256 + tid;       // 0..32767
        const int d = idx >> 7, r = idx & 127;
        VdT[idx] = f2bf(NEG_LOG2E * Vd[(size_t)r * Dn + d]);
        if (bi == BNn && tid < 4) stats[tid] = 0.0f;
        return;
    }
    __shared__ float trow[Dn];
    trow[tid] = t[(size_t)bi * Dn + tid];
    __syncthreads();
    // qd / kd (bf16): all 256 threads, one output col each
    {
        const float* W = (tid < 128) ? Qd : Kd;
        ushort* ob = (tid < 128) ? qdb : kdb;
        const int col = tid & 127;
        float a0 = 0.f;
        for (int kk = 0; kk < Dn; kk += 4) {
            float4 tv = *(const float4*)&trow[kk];
            a0 += tv.x * W[(size_t)(kk + 0) * 128 + col]
                + tv.y * W[(size_t)(kk + 1) * 128 + col]
                + tv.z * W[(size_t)(kk + 2) * 128 + col]
                + tv.w * W[(size_t)(kk + 3) * 128 + col];
        }
        ob[(size_t)bi * 128 + col] = f2bf(a0);
    }
    // q / k (fp32): threads < 128, one output col each
    if (tid < 128) {
        const float* W = (tid < 64) ? Qs : Ks;
        float* of = (tid < 64) ? q : k;
        const int col = tid & 63;
        float a0 = 0.f;
        for (int kk = 0; kk < Dn; kk += 4) {
            float4 tv = *(const float4*)&trow[kk];
            a0 += tv.x * W[(size_t)(kk + 0) * 64 + col]
                + tv.y * W[(size_t)(kk + 1) * 64 + col]
                + tv.z * W[(size_t)(kk + 2) * 64 + col]
                + tv.w * W[(size_t)(kk + 3) * 64 + col];
        }
        of[(size_t)bi * 64 + col] = a0;
    }
}

// ================= K2: s_sym + off-diag stats (shfl-based reduction) =================
__global__ __launch_bounds__(256)
void ssym_kernel(const float* __restrict__ q, const float* __restrict__ k,
                 float* __restrict__ ssym, float* __restrict__ stats) {
    __shared__ float qi[16][68], ki[16][68], qj[16][68], kj[16][68];
    __shared__ float part[8];
    const int b = blockIdx.z, it = blockIdx.x, jt = blockIdx.y;
    const int tid = threadIdx.x;
    const int r0 = tid >> 6, c = tid & 63;
#pragma unroll
    for (int p = 0; p < 4; ++p) {
        int row = r0 + 4 * p;
        qi[row][c] = q[((size_t)(b * Nn + it * 16 + row)) * Sn + c];
        ki[row][c] = k[((size_t)(b * Nn + it * 16 + row)) * Sn + c];
        qj[row][c] = q[((size_t)(b * Nn + jt * 16 + row)) * Sn + c];
        kj[row][c] = k[((size_t)(b * Nn + jt * 16 + row)) * Sn + c];
    }
    __syncthreads();
    const int ti = tid >> 4, tj = tid & 15;
    float acc = 0.0f;
#pragma unroll
    for (int dd = 0; dd < Sn; dd += 4) {
        float4 a  = *(const float4*)&qi[ti][dd];
        float4 bb = *(const float4*)&kj[tj][dd];
        float4 cc = *(const float4*)&qj[tj][dd];
        float4 d  = *(const float4*)&ki[ti][dd];
        acc += a.x * bb.x + a.y * bb.y + a.z * bb.z + a.w * bb.w
             + cc.x * d.x + cc.y * d.y + cc.z * d.z + cc.w * d.w;
    }
    const float sval = acc * 0.0625f;
    const int gi = it * 16 + ti, gj = jt * 16 + tj;
    ssym[((size_t)(b * Nn + gi)) * Nn + gj] = sval;
    const float v = (gi == gj) ? 0.0f : sval;

    float vs = v, v2 = v * v;
#pragma unroll
    for (int mask = 32; mask > 0; mask >>= 1) {
        vs += __shfl_xor(vs, mask);
        v2 += __shfl_xor(v2, mask);
    }
    const int lane = tid & 63, wave = tid >> 6;
    if (lane == 0) { part[wave] = vs; part[4 + wave] = v2; }
    __syncthreads();
    if (tid == 0) {
        atomicAdd(&stats[b * 2 + 0], part[0] + part[1] + part[2] + part[3]);
        atomicAdd(&stats[b * 2 + 1], part[4] + part[5] + part[6] + part[7]);
    }
}

// ================= K3: m[row] (stats finalized inline) =================
__global__ __launch_bounds__(256)
void m_kernel(const float* __restrict__ ssym, const float* __restrict__ stats,
              const float* __restrict__ a_l, const float* __restrict__ b_l,
              float* __restrict__ m) {
    __shared__ float part[4];
    const int row = blockIdx.x;
    const int b = row / Nn;
    const float cnt_inv = 1.0f / (float)(Nn * (Nn - 1));
    const float mu = stats[b * 2 + 0] * cnt_inv;
    const float var = stats[b * 2 + 1] * cnt_inv - mu * mu;
    const float isg = rsqrtf(var + 1e-6f);
    const float a = a_l[0], bbias = b_l[0];
    const int tid = threadIdx.x;
    float sum = __expf(a * (ssym[(size_t)row * Nn + tid] - mu) * isg + bbias);
    if (tid < 128)
        sum += __expf(a * (ssym[(size_t)row * Nn + 256 + tid] - mu) * isg + bbias);
#pragma unroll
    for (int mask = 32; mask > 0; mask >>= 1) sum += __shfl_xor(sum, mask);
    if ((tid & 63) == 0) part[tid >> 6] = sum;
    __syncthreads();
    if (tid == 0) m[row] = 1.0f / (part[0] + part[1] + part[2] + part[3] + 1e-6f);
}

// ================= K4: pair kernel v8 — 8-wave blocks, d-half split ====================
// kappa_diff (scaled by -log2e) = U - W:
//   U = MFMA(A = u[d,r], B = kd_j[r]),  u = VdT_scaled[d,r] * qd_i[r]
//   W = MFMA(A = w[d,r], B = qd_j[r]),  w = VdT_scaled[d,r] * kd_i[r]
// grid 2*BNn x 512 thr: blk>>1 = (b,i), blk&1 = d-half. 8 waves x 16 d each.
// HISTORY (do not regress):
//   r1: (256,6) -> 40-VGPR cap -> spill (640 MB HBM). Never cap below natural alloc.
//   r3: 64 persistent A-frag VGPRs (32 d/wave) -> peak ~140 > 128 -> spill. 16 d/wave.
//   r4: global-direct B gathers -> latency-bound (4.6% MFMA). B must be LDS-fed.
//   r5: row-major LDS + bad XOR -> 9.4M conflicts -- BUT fixing them (r7) changed
//       nothing: conflicts were not the critical path.
//   r6: frag-permutation on the GLOBAL side -> 16-seg gathers -> 1.6x slower. Keep
//       global loads coalesced; permute in ds_write addrs only.
//   r7: conflict-free + coalesced, 81.5us, VALUBusy 44 / Mfma 20 / Occ 39: epilogue-
//       (VALU/trans-)limited at ~44% duty; stall = occupancy (4 waves/block, LDS-capped
//       4 blocks/CU = 16 waves/CU). v8: 8-wave blocks halve LDS per wave -> 32 waves/CU.
// LDS slot(jr,ch) byte = (jr>>4)*4096 + (ch>>2)*1024 + (ch&3)*256 + (((jr&15)^(ch&7))*16)
//   - global: thread tid loads row tid>>4, chunk tid&15 -> coalesced
//   - ds_write col (jr^ch)&7 uniform; ds_read col (ln^((ks&1)*4+quad))&7 uniform.
__global__ __launch_bounds__(512, 4)
void pair_kernel(const float* __restrict__ t, const float* __restrict__ ssym,
                 const float* __restrict__ mptr, const float* __restrict__ stats,
                 const float* __restrict__ a_l, const float* __restrict__ b_l,
                 const ushort* __restrict__ qdb, const ushort* __restrict__ kdb,
                 const ushort* __restrict__ VdT, float* __restrict__ out) {
    __shared__ ushort qs_lds[2][4096];   // 2 x 8 KB, frag-ordered+swizzled
    __shared__ ushort ks_lds[2][4096];   // 2 x 8 KB
    __shared__ float alpha_s[Nn];
    __shared__ float part[8];

    const int blk = blockIdx.x;
    const int bi = blk >> 1;
    const int dh = blk & 1;
    const int b = bi / Nn;
    const int i = bi - b * Nn;
    const int tid = threadIdx.x;
    const int wave = tid >> 6, lane = tid & 63;
    const int ln = lane & 15, quad = lane >> 4;
    const int wd0 = dh * 128 + wave * 16;    // this wave's 16-d row tile

    // ---- inline alpha row (shfl reduce across 8 waves) ----
    {
        const float cnt_inv = 1.0f / (float)(Nn * (Nn - 1));
        const float mu = stats[b * 2 + 0] * cnt_inv;
        const float var = stats[b * 2 + 1] * cnt_inv - mu * mu;
        const float isg = rsqrtf(var + 1e-6f);
        const float a = a_l[0], bbias = b_l[0];
        float A0 = 0.f, am0 = 0.f;
        if (tid < Nn) {
            float s0 = ssym[(size_t)bi * Nn + tid];
            A0 = fast_sigmoid(a * (s0 - mu) * isg + bbias);
            am0 = A0 * mptr[b * Nn + tid];
        }
        float sum = am0;
#pragma unroll
        for (int mask = 32; mask > 0; mask >>= 1) sum += __shfl_xor(sum, mask);
        if (lane == 0) part[wave] = sum;
        __syncthreads();
        const float tot = part[0] + part[1] + part[2] + part[3]
                        + part[4] + part[5] + part[6] + part[7];
        const float inv = 1.0f / (tot + 1e-6f);
        if (tid < Nn)
            alpha_s[tid] = (tid == i) ? 0.f : A0 * am0 * inv;
        // visibility covered by the prologue barrier below
    }

    // ---- one-time: A-fragments u = VdTs*qd_i, w = VdTs*kd_i (bf16), 8 short8 = 32 VGPR ----
    // A layout (16x16x32): m = ln (d within 16), k = quad*8+e, r = ks*32 + k.
    short8 uf[4], wf[4];
    {
        const size_t qrow = (size_t)bi * Rn;
#pragma unroll
        for (int ks = 0; ks < 4; ++ks) {
            short8 qv = *(const short8*)&qdb[qrow + ks * 32 + quad * 8];
            short8 kv = *(const short8*)&kdb[qrow + ks * 32 + quad * 8];
            short8 vv = *(const short8*)&VdT[(size_t)(wd0 + ln) * Rn + ks * 32 + quad * 8];
            short8 uu, ww;
#pragma unroll
            for (int e = 0; e < 8; ++e) {
                float vf_ = bf2f((ushort)vv[e]);
                uu[e] = (short)f2bf(vf_ * bf2f((ushort)qv[e]));
                ww[e] = (short)f2bf(vf_ * bf2f((ushort)kv[e]));
            }
            uf[ks] = uu;
            wf[ks] = ww;
        }
    }

    float4 tiv = *(const float4*)&t[(size_t)bi * Dn + wd0 + quad * 4];
    float4 outac = make_float4(0.f, 0.f, 0.f, 0.f);

    const ushort* qsrc = qdb + (size_t)b * Nn * Rn;
    const ushort* ksrc = kdb + (size_t)b * Nn * Rn;
    const float* tbase_ = t + (size_t)b * Nn * Dn + wd0 + quad * 4;

    // staging: 512 threads cover the whole 32-row tile in ONE uint4 per array.
    // thread tid: global row tid>>4 (0..31), chunk tid&15 -> wave = 4 contiguous rows.
    const int jr = tid >> 4;                          // 0..31
    const int ch = tid & 15;                          // 16B chunk
    const int wb = (jr >> 4) * 4096 + (ch >> 2) * 1024 + (ch & 3) * 256
                 + (((jr & 15) ^ (ch & 7)) * 16);

    uint4 sq, sk;

    // ---- prologue: stage tile 0 into buf 0 ----
    {
        const ushort* q0 = qsrc + (size_t)jr * Rn + ch * 8;
        const ushort* k0 = ksrc + (size_t)jr * Rn + ch * 8;
        sq = *(const uint4*)q0;
        sk = *(const uint4*)k0;
        *(uint4*)((char*)&qs_lds[0][0] + wb) = sq;
        *(uint4*)((char*)&ks_lds[0][0] + wb) = sk;
    }
    __syncthreads();

    // read-side swizzled lane term: addr(s,ks) = s*4096 + ks*1024 + (lane_off ^ ((ks&1)<<6))
    const int lane_off = ((ln ^ quad) * 16) + quad * 256;

    // tj prefetch for first subtile
    float4 tj_cur = *(const float4*)&tbase_[(size_t)ln * Dn];

    int cur = 0;
#pragma unroll 1
    for (int tt = 0; tt < Nn / 32; ++tt) {
        // issue next-tile stage loads early (latency hides under this tile's compute)
        const int tn = (tt + 1 < Nn / 32) ? tt + 1 : 0;   // wrapped: last prefetch unused
        {
            const ushort* q0 = qsrc + (size_t)(tn * 32 + jr) * Rn + ch * 8;
            const ushort* k0 = ksrc + (size_t)(tn * 32 + jr) * Rn + ch * 8;
            sq = *(const uint4*)q0;
            sk = *(const uint4*)k0;
        }

        const char* qbuf = (const char*)&qs_lds[cur][0];
        const char* kbuf = (const char*)&ks_lds[cur][0];

        // ---- 2 j-subtiles of 16 from LDS ----
#pragma unroll
        for (int s = 0; s < 2; ++s) {
            const int jj = tt * 2 + s;
            const int jn = (jj + 1 < Nn / 16) ? jj + 1 : 0;
            // prefetch tj for the NEXT subtile; current one already in tj_cur
            float4 tj_nxt = *(const float4*)&tbase_[(size_t)(jn * 16 + ln) * Dn];

            f32x4 accU = {0.f, 0.f, 0.f, 0.f}, accW = {0.f, 0.f, 0.f, 0.f};
#pragma unroll
            for (int ks = 0; ks < 4; ++ks) {
                const int off = s * 4096 + ks * 1024 + (lane_off ^ ((ks & 1) << 6));
                short8 bk = *(const short8*)(kbuf + off);
                short8 bq = *(const short8*)(qbuf + off);
                accU = __builtin_amdgcn_mfma_f32_16x16x32_bf16(uf[ks], bk, accU, 0, 0, 0);
                accW = __builtin_amdgcn_mfma_f32_16x16x32_bf16(wf[ks], bq, accW, 0, 0, 0);
            }
            const float al = alpha_s[jj * 16 + ln];
            float e0 = accU[0] - accW[0];
            float e1 = accU[1] - accW[1];
            float e2 = accU[2] - accW[2];
            float e3 = accU[3] - accW[3];
            float g0 = __builtin_amdgcn_rcpf(1.0f + __builtin_amdgcn_exp2f(e0));
            float g1 = __builtin_amdgcn_rcpf(1.0f + __builtin_amdgcn_exp2f(e1));
            float g2 = __builtin_amdgcn_rcpf(1.0f + __builtin_amdgcn_exp2f(e2));
            float g3 = __builtin_amdgcn_rcpf(1.0f + __builtin_amdgcn_exp2f(e3));
            outac.x += al * g0 * (tiv.x - tj_cur.x);
            outac.y += al * g1 * (tiv.y - tj_cur.y);
            outac.z += al * g2 * (tiv.z - tj_cur.z);
            outac.w += al * g3 * (tiv.w - tj_cur.w);
            tj_cur = tj_nxt;
        }

        // ---- write next tile into the other buffer, then the tile barrier ----
        {
            *(uint4*)((char*)&qs_lds[cur ^ 1][0] + wb) = sq;
            *(uint4*)((char*)&ks_lds[cur ^ 1][0] + wb) = sk;
        }
        __syncthreads();
        cur ^= 1;
    }

    // ---- reduce over the 16 j-lanes, write 16 d per wave ----
    {
        float4 v = outac;
#pragma unroll
        for (int mask = 1; mask < 16; mask <<= 1) {
            v.x += __shfl_xor(v.x, mask);
            v.y += __shfl_xor(v.y, mask);
            v.z += __shfl_xor(v.z, mask);
            v.w += __shfl_xor(v.w, mask);
        }
        if (ln == 0) {
            float4 o;
            o.x = tiv.x - v.x;
            o.y = tiv.y - v.y;
            o.z = tiv.z - v.z;
            o.w = tiv.w - v.w;
            *(float4*)&out[(size_t)bi * Dn + wd0 + quad * 4] = o;
        }
    }
}

extern "C" void kernel_launch(void* const* d_in, const int* in_sizes, int n_in,
                              void* d_out, int out_size, void* d_ws, size_t ws_size,
                              hipStream_t stream) {
    const float* t   = (const float*)d_in[0];
    const float* Qd  = (const float*)d_in[1];
    const float* Kd  = (const float*)d_in[2];
    const float* Vd  = (const float*)d_in[3];
    const float* Qs  = (const float*)d_in[4];
    const float* Ks  = (const float*)d_in[5];
    const float* a_l = (const float*)d_in[6];
    const float* b_l = (const float*)d_in[7];
    float* out = (float*)d_out;
    float* ws  = (float*)d_ws;

    float* q     = ws;                          // 768*64
    float* k     = q + BNn * Sn;                // 768*64
    float* ssym  = k + BNn * Sn;                // 768*384
    float* m     = ssym + (size_t)BNn * Nn;     // 768
    float* stats = m + BNn;                     // 8
    ushort* qdb  = (ushort*)(stats + 8);        // 768*128 bf16
    ushort* kdb  = qdb + (size_t)BNn * Rn;      // 768*128 bf16
    ushort* VdT  = kdb + (size_t)BNn * Rn;      // 256*128 bf16 (pre-scaled by -log2e)

    hipLaunchKernelGGL(prep_kernel, dim3(BNn + 128), dim3(256), 0, stream,
                       t, Qd, Kd, Vd, Qs, Ks, q, k, qdb, kdb, VdT, stats);
    hipLaunchKernelGGL(ssym_kernel, dim3(Nn / 16, Nn / 16, Bn), dim3(256), 0, stream,
                       q, k, ssym, stats);
    hipLaunchKernelGGL(m_kernel, dim3(BNn), dim3(256), 0, stream, ssym, stats, a_l, b_l, m);
    hipLaunchKernelGGL(pair_kernel, dim3(BNn * 2), dim3(512), 0, stream,
                       t, ssym, m, stats, a_l, b_l, qdb, kdb, VdT, out);
}